// Round 1
// baseline (195.615 us; speedup 1.0000x reference)
//
#include <hip/hip_runtime.h>
#include <hip/hip_bf16.h>
#include <math.h>

// Problem constants
#define BB 16
#define TT 64
#define HWXY 512   // H*W
#define EE 256
#define VV 128

typedef __bf16 bf16x8 __attribute__((ext_vector_type(8)));
typedef unsigned short u16x8 __attribute__((ext_vector_type(8)));
typedef float f32x4 __attribute__((ext_vector_type(4)));

__device__ __forceinline__ f32x4 mfma16(bf16x8 a, bf16x8 b, f32x4 c) {
    return __builtin_amdgcn_mfma_f32_16x16x32_bf16(a, b, c, 0, 0, 0);
}

__device__ __forceinline__ unsigned short f2bf(float f) {
    union { float f; unsigned int i; } v; v.f = f;
    unsigned int x = v.i;
    unsigned int r = (x + 0x7fffu + ((x >> 16) & 1u)) >> 16;  // RNE
    return (unsigned short)r;
}

__device__ __forceinline__ bf16x8 load_bf8(const unsigned short* p) {
    return __builtin_bit_cast(bf16x8, *(const u16x8*)p);
}

// ---------------------------------------------------------------------------
// Setup: embed gather, bf16 packs, transposes
// ---------------------------------------------------------------------------
__global__ __launch_bounds__(256) void k_setup(
    const float* __restrict__ enc, const float* __restrict__ dec,
    const int* __restrict__ labels, const float* __restrict__ embed,
    const float* __restrict__ conv_w, const float* __restrict__ W_w,
    const float* __restrict__ Wo_w,
    float* __restrict__ s_f32, unsigned short* __restrict__ a_bf,
    unsigned short* __restrict__ dec_bf, unsigned short* __restrict__ resT,
    unsigned short* __restrict__ convwT, unsigned short* __restrict__ W_bf,
    unsigned short* __restrict__ Wo_bf) {
    int idx = blockIdx.x * 256 + threadIdx.x;
    const int n1 = BB * TT * EE;          // 262144  s & a0
    const int n2 = BB * HWXY * EE;        // 2097152 dec_bf
    const int n3 = n2;                    //         resT
    const int n4 = 512 * 768;             // 393216  convwT
    const int n5 = EE * EE;               // 65536
    const int n6 = VV * EE;               // 32768
    if (idx < n1) {
        int b = idx / (TT * EE);
        int r = idx % (TT * EE);
        int t = r / EE, e = r % EE;
        int lab = labels[b * TT + t];
        float v = embed[lab * EE + e];
        s_f32[idx] = v;
        a_bf[idx] = f2bf(v);
        return;
    }
    idx -= n1;
    if (idx < n2) { dec_bf[idx] = f2bf(dec[idx]); return; }
    idx -= n2;
    if (idx < n3) {
        int b = idx / (EE * HWXY);
        int r = idx % (EE * HWXY);
        int e = r / HWXY, s = r % HWXY;
        int src = (b * HWXY + s) * EE + e;
        resT[idx] = f2bf(enc[src] + dec[src]);
        return;
    }
    idx -= n3;
    if (idx < n4) {
        int j = idx / 768, kk = idx % 768;
        int kt = kk >> 8, e = kk & 255;
        convwT[idx] = f2bf(conv_w[(kt * EE + e) * 512 + j]);
        return;
    }
    idx -= n4;
    if (idx < n5) { W_bf[idx] = f2bf(W_w[idx]); return; }
    idx -= n5;
    if (idx < n6) { Wo_bf[idx] = f2bf(Wo_w[idx]); }
}

// ---------------------------------------------------------------------------
// Conv(K=3, E -> 2E) + GLU  -> z (f32 + bf16)
// GEMM M=1024(bt) x Npair=256 x K=768 with t-halo masking, no LDS.
// grid (32, 4), block 256: wave computes 16 rows x 32 pair-cols (za and zb)
// ---------------------------------------------------------------------------
__global__ __launch_bounds__(256) void k_conv_glu(
    const unsigned short* __restrict__ a_bf, const unsigned short* __restrict__ convwT,
    const float* __restrict__ conv_b, float* __restrict__ z_f32,
    unsigned short* __restrict__ z_bf) {
    const int mt = blockIdx.x, nt = blockIdx.y;
    const int w = threadIdx.x >> 6, L = threadIdx.x & 63;
    const int l16 = L & 15, lg = L >> 4;
    const int rbase = mt * 32 + (w >> 1) * 16;
    const int cbase = nt * 64 + (w & 1) * 32;
    f32x4 za[2] = {{0.f,0.f,0.f,0.f},{0.f,0.f,0.f,0.f}};
    f32x4 zb[2] = {{0.f,0.f,0.f,0.f},{0.f,0.f,0.f,0.f}};
    const int rowA = rbase + l16;
    const int bb = rowA >> 6, tA = rowA & 63;
    for (int kc = 0; kc < 24; ++kc) {
        const int kt = kc >> 3;             // tap 0..2
        const int e0 = (kc & 7) * 32;       // e offset within tap
        const int ts = tA + kt - 1;
        u16x8 au = (u16x8)0;
        if (ts >= 0 && ts < TT)
            au = *(const u16x8*)(a_bf + ((bb << 6) + ts) * EE + e0 + lg * 8);
        bf16x8 af = __builtin_bit_cast(bf16x8, au);
        const int k0 = kc * 32;
#pragma unroll
        for (int nf = 0; nf < 2; ++nf) {
            int j = cbase + nf * 16 + l16;
            bf16x8 b0 = load_bf8(convwT + j * 768 + k0 + lg * 8);
            bf16x8 b1 = load_bf8(convwT + (j + 256) * 768 + k0 + lg * 8);
            za[nf] = mfma16(af, b0, za[nf]);
            zb[nf] = mfma16(af, b1, zb[nf]);
        }
    }
#pragma unroll
    for (int nf = 0; nf < 2; ++nf) {
        int p = cbase + nf * 16 + l16;
        float cbA = conv_b[p], cbB = conv_b[p + 256];
#pragma unroll
        for (int j = 0; j < 4; ++j) {
            int row = rbase + lg * 4 + j;
            float vA = za[nf][j] + cbA;
            float vB = zb[nf][j] + cbB;
            float zv = vA / (1.0f + __expf(-vB));
            int idx = row * EE + p;
            z_f32[idx] = zv;
            z_bf[idx] = f2bf(zv);
        }
    }
}

// ---------------------------------------------------------------------------
// h = z @ W^T + W_b + s  -> h_bf16.  M=1024, N=256, K=256. grid (32,4)
// ---------------------------------------------------------------------------
__global__ __launch_bounds__(256) void k_h(
    const unsigned short* __restrict__ z_bf, const unsigned short* __restrict__ W_bf,
    const float* __restrict__ W_b, const float* __restrict__ s_f32,
    unsigned short* __restrict__ h_bf) {
    const int mt = blockIdx.x, nt = blockIdx.y;
    const int w = threadIdx.x >> 6, L = threadIdx.x & 63;
    const int l16 = L & 15, lg = L >> 4;
    const int rbase = mt * 32 + (w >> 1) * 16;
    const int cbase = nt * 64 + (w & 1) * 32;
    f32x4 acc[2] = {{0.f,0.f,0.f,0.f},{0.f,0.f,0.f,0.f}};
    const int rowA = rbase + l16;
    for (int kc = 0; kc < 8; ++kc) {
        bf16x8 af = load_bf8(z_bf + rowA * EE + kc * 32 + lg * 8);
#pragma unroll
        for (int nf = 0; nf < 2; ++nf) {
            int c = cbase + nf * 16 + l16;
            bf16x8 bf = load_bf8(W_bf + c * EE + kc * 32 + lg * 8);
            acc[nf] = mfma16(af, bf, acc[nf]);
        }
    }
#pragma unroll
    for (int nf = 0; nf < 2; ++nf) {
        int c = cbase + nf * 16 + l16;
        float wb = W_b[c];
#pragma unroll
        for (int j = 0; j < 4; ++j) {
            int row = rbase + lg * 4 + j;
            int idx = row * EE + c;
            h_bf[idx] = f2bf(acc[nf][j] + wb + s_f32[idx]);
        }
    }
}

// ---------------------------------------------------------------------------
// scores[b,t,s] = h[b,t,:] . dec[b,s,:]   M=64, N=512, K=256 per batch
// grid (16, 8): (b, s-tile of 64). wave w: t-rows [16w,16w+16)
// ---------------------------------------------------------------------------
__global__ __launch_bounds__(256) void k_scores(
    const unsigned short* __restrict__ h_bf, const unsigned short* __restrict__ dec_bf,
    float* __restrict__ scores) {
    const int b = blockIdx.x, nt = blockIdx.y;
    const int w = threadIdx.x >> 6, L = threadIdx.x & 63;
    const int l16 = L & 15, lg = L >> 4;
    f32x4 acc[4] = {{0.f,0.f,0.f,0.f},{0.f,0.f,0.f,0.f},{0.f,0.f,0.f,0.f},{0.f,0.f,0.f,0.f}};
    const int rowA = b * TT + w * 16 + l16;
    for (int kc = 0; kc < 8; ++kc) {
        bf16x8 af = load_bf8(h_bf + rowA * EE + kc * 32 + lg * 8);
#pragma unroll
        for (int nf = 0; nf < 4; ++nf) {
            int srow = nt * 64 + nf * 16 + l16;
            bf16x8 bf = load_bf8(dec_bf + (b * HWXY + srow) * EE + kc * 32 + lg * 8);
            acc[nf] = mfma16(af, bf, acc[nf]);
        }
    }
#pragma unroll
    for (int nf = 0; nf < 4; ++nf)
#pragma unroll
        for (int j = 0; j < 4; ++j) {
            int t = w * 16 + lg * 4 + j;
            int sc = nt * 64 + nf * 16 + l16;
            scores[(b * TT + t) * HWXY + sc] = acc[nf][j];
        }
}

// ---------------------------------------------------------------------------
// softmax over s (512) + c = alpha . residual + z -> new a (bf16)
// grid 64 = (b, t-tile of 16). block 256.
// Phase1: softmax rows into swizzled LDS (bf16). Phase2: MFMA [16,512]x[512,64/wave]
// ---------------------------------------------------------------------------
__global__ __launch_bounds__(256) void k_softmax_c(
    const float* __restrict__ scores, const unsigned short* __restrict__ resT,
    const float* __restrict__ z_f32, unsigned short* __restrict__ a_bf) {
    __shared__ char lds[16 * 1024];   // 16 rows x 512 bf16, XOR-swizzled 16B chunks
    const int b = blockIdx.x >> 2, tt = blockIdx.x & 3;
    const int t0 = tt * 16;
    const int w = threadIdx.x >> 6, L = threadIdx.x & 63;
    const int l16 = L & 15, lg = L >> 4;

    // Phase 1: each wave handles 4 rows; 64 lanes x 8 f32 = 512 per row
    for (int i = 0; i < 4; ++i) {
        int row = w * 4 + i;
        const float* sp = scores + (b * TT + t0 + row) * HWXY + L * 8;
        float4 v0 = *(const float4*)sp;
        float4 v1 = *(const float4*)(sp + 4);
        float v[8] = {v0.x, v0.y, v0.z, v0.w, v1.x, v1.y, v1.z, v1.w};
        float m = v[0];
#pragma unroll
        for (int k = 1; k < 8; ++k) m = fmaxf(m, v[k]);
#pragma unroll
        for (int off = 32; off >= 1; off >>= 1) m = fmaxf(m, __shfl_xor(m, off));
        float p[8], sum = 0.f;
#pragma unroll
        for (int k = 0; k < 8; ++k) { p[k] = __expf(v[k] - m); sum += p[k]; }
#pragma unroll
        for (int off = 32; off >= 1; off >>= 1) sum += __shfl_xor(sum, off);
        float inv = 1.0f / sum;
        u16x8 pk;
#pragma unroll
        for (int k = 0; k < 8; ++k) pk[k] = f2bf(p[k] * inv);
        int byteoff = (L * 16) ^ ((row & 7) << 4);
        *(u16x8*)(lds + row * 1024 + byteoff) = pk;
    }
    __syncthreads();

    // Phase 2: c[t, e-tile(w)] = alpha x res^T ; add z; write a
    f32x4 acc[4] = {{0.f,0.f,0.f,0.f},{0.f,0.f,0.f,0.f},{0.f,0.f,0.f,0.f},{0.f,0.f,0.f,0.f}};
    for (int kc = 0; kc < 16; ++kc) {
        int k0 = kc * 32;
        int abyte = ((k0 + lg * 8) * 2) ^ ((l16 & 7) << 4);
        bf16x8 af = __builtin_bit_cast(bf16x8, *(const u16x8*)(lds + l16 * 1024 + abyte));
#pragma unroll
        for (int nf = 0; nf < 4; ++nf) {
            int e = w * 64 + nf * 16 + l16;
            bf16x8 bf = load_bf8(resT + (b * EE + e) * HWXY + k0 + lg * 8);
            acc[nf] = mfma16(af, bf, acc[nf]);
        }
    }
#pragma unroll
    for (int nf = 0; nf < 4; ++nf)
#pragma unroll
        for (int j = 0; j < 4; ++j) {
            int t = t0 + lg * 4 + j;
            int e = w * 64 + nf * 16 + l16;
            int idx = (b * TT + t) * EE + e;
            a_bf[idx] = f2bf(acc[nf][j] + z_f32[idx]);
        }
}

// ---------------------------------------------------------------------------
// logits = a @ Wo^T + Wo_b ; log_softmax over V=128. grid 16, block 256.
// wave: 16 rows x 128 cols (8 n-frags), then 16-lane-group reduction.
// ---------------------------------------------------------------------------
__global__ __launch_bounds__(256) void k_logits(
    const unsigned short* __restrict__ a_bf, const unsigned short* __restrict__ Wo_bf,
    const float* __restrict__ Wo_b, float* __restrict__ out) {
    const int g = blockIdx.x;
    const int w = threadIdx.x >> 6, L = threadIdx.x & 63;
    const int l16 = L & 15, lg = L >> 4;
    const int r0 = g * 64 + w * 16;
    f32x4 acc[8] = {{0.f,0.f,0.f,0.f},{0.f,0.f,0.f,0.f},{0.f,0.f,0.f,0.f},{0.f,0.f,0.f,0.f},
                    {0.f,0.f,0.f,0.f},{0.f,0.f,0.f,0.f},{0.f,0.f,0.f,0.f},{0.f,0.f,0.f,0.f}};
    const int rowA = r0 + l16;
    for (int kc = 0; kc < 8; ++kc) {
        bf16x8 af = load_bf8(a_bf + rowA * EE + kc * 32 + lg * 8);
#pragma unroll
        for (int nf = 0; nf < 8; ++nf) {
            bf16x8 bf = load_bf8(Wo_bf + (nf * 16 + l16) * EE + kc * 32 + lg * 8);
            acc[nf] = mfma16(af, bf, acc[nf]);
        }
    }
#pragma unroll
    for (int j = 0; j < 4; ++j) {
        int row = r0 + lg * 4 + j;
        float v[8];
#pragma unroll
        for (int nf = 0; nf < 8; ++nf) v[nf] = acc[nf][j] + Wo_b[nf * 16 + l16];
        float m = v[0];
#pragma unroll
        for (int nf = 1; nf < 8; ++nf) m = fmaxf(m, v[nf]);
#pragma unroll
        for (int off = 8; off >= 1; off >>= 1) m = fmaxf(m, __shfl_xor(m, off));
        float sum = 0.f;
#pragma unroll
        for (int nf = 0; nf < 8; ++nf) sum += __expf(v[nf] - m);
#pragma unroll
        for (int off = 8; off >= 1; off >>= 1) sum += __shfl_xor(sum, off);
        float lse = m + __logf(sum);
#pragma unroll
        for (int nf = 0; nf < 8; ++nf)
            out[row * VV + nf * 16 + l16] = v[nf] - lse;
    }
}

// ---------------------------------------------------------------------------
extern "C" void kernel_launch(void* const* d_in, const int* in_sizes, int n_in,
                              void* d_out, int out_size, void* d_ws, size_t ws_size,
                              hipStream_t stream) {
    const float* enc    = (const float*)d_in[0];
    const float* dec    = (const float*)d_in[1];
    const int*   labels = (const int*)d_in[2];
    const float* embed  = (const float*)d_in[3];
    const float* conv_w = (const float*)d_in[4];
    const float* conv_b = (const float*)d_in[5];
    const float* W_w    = (const float*)d_in[6];
    const float* W_b    = (const float*)d_in[7];
    const float* Wo_w   = (const float*)d_in[8];
    const float* Wo_b   = (const float*)d_in[9];
    float* out = (float*)d_out;
    char* ws = (char*)d_ws;

    float*          s_f32  = (float*)(ws + 0);
    float*          z_f32  = (float*)(ws + 1048576);
    float*          scores = (float*)(ws + 2097152);
    unsigned short* a_bf   = (unsigned short*)(ws + 4194304);
    unsigned short* z_bf   = (unsigned short*)(ws + 4718592);
    unsigned short* h_bf   = (unsigned short*)(ws + 5242880);
    unsigned short* dec_bf = (unsigned short*)(ws + 5767168);
    unsigned short* resT   = (unsigned short*)(ws + 9961472);
    unsigned short* convwT = (unsigned short*)(ws + 14155776);
    unsigned short* W_bf   = (unsigned short*)(ws + 14942208);
    unsigned short* Wo_bf  = (unsigned short*)(ws + 15073280);

    const int total = 262144 + 2097152 + 2097152 + 393216 + 65536 + 32768;
    k_setup<<<(total + 255) / 256, 256, 0, stream>>>(
        enc, dec, labels, embed, conv_w, W_w, Wo_w,
        s_f32, a_bf, dec_bf, resT, convwT, W_bf, Wo_bf);

    for (int l = 0; l < 3; ++l) {
        k_conv_glu<<<dim3(32, 4), 256, 0, stream>>>(a_bf, convwT, conv_b, z_f32, z_bf);
        k_h<<<dim3(32, 4), 256, 0, stream>>>(z_bf, W_bf, W_b, s_f32, h_bf);
        k_scores<<<dim3(16, 8), 256, 0, stream>>>(h_bf, dec_bf, scores);
        k_softmax_c<<<64, 256, 0, stream>>>(scores, resT, z_f32, a_bf);
    }
    k_logits<<<16, 256, 0, stream>>>(a_bf, Wo_bf, Wo_b, out);
}

// Round 2
// 161.856 us; speedup vs baseline: 1.2086x; 1.2086x over previous
//
#include <hip/hip_runtime.h>
#include <hip/hip_bf16.h>
#include <math.h>

#define BB 16
#define TT 64
#define HWXY 512
#define EE 256
#define VV 128

typedef __bf16 bf16x8 __attribute__((ext_vector_type(8)));
typedef unsigned short u16x8 __attribute__((ext_vector_type(8)));
typedef float f32x4 __attribute__((ext_vector_type(4)));

__device__ __forceinline__ f32x4 mfma16(bf16x8 a, bf16x8 b, f32x4 c) {
    return __builtin_amdgcn_mfma_f32_16x16x32_bf16(a, b, c, 0, 0, 0);
}

__device__ __forceinline__ unsigned short f2bf(float f) {
    union { float f; unsigned int i; } v; v.f = f;
    unsigned int x = v.i;
    return (unsigned short)((x + 0x7fffu + ((x >> 16) & 1u)) >> 16);  // RNE
}

__device__ __forceinline__ bf16x8 load_bf8(const unsigned short* p) {
    return __builtin_bit_cast(bf16x8, *(const u16x8*)p);
}

__device__ __forceinline__ u16x8 pack8(float4 v0, float4 v1) {
    u16x8 o;
    o[0] = f2bf(v0.x); o[1] = f2bf(v0.y); o[2] = f2bf(v0.z); o[3] = f2bf(v0.w);
    o[4] = f2bf(v1.x); o[5] = f2bf(v1.y); o[6] = f2bf(v1.z); o[7] = f2bf(v1.w);
    return o;
}

// ---------------------------------------------------------------------------
// Unified setup: LDS-tiled transposes (resT, convwT) + vectorized elementwise
// grid layout: [0,512) resT tiles (+dec_bf), [512,608) convwT tiles,
//              [608,784) elementwise (embed gather, W, Wo)
// ---------------------------------------------------------------------------
__global__ __launch_bounds__(256) void k_setup(
    const float* __restrict__ enc, const float* __restrict__ dec,
    const int* __restrict__ labels, const float* __restrict__ embed,
    const float* __restrict__ conv_w, const float* __restrict__ W_w,
    const float* __restrict__ Wo_w,
    float* __restrict__ s_f32, unsigned short* __restrict__ a_bf,
    unsigned short* __restrict__ dec_bf, unsigned short* __restrict__ resT,
    unsigned short* __restrict__ convwT, unsigned short* __restrict__ W_bf,
    unsigned short* __restrict__ Wo_bf) {
    __shared__ unsigned short tl[64][66];   // padded: stride 132B -> 2-way max
    int bid = blockIdx.x;
    if (bid < 512) {
        // resT[b][e][s] = bf16(enc+dec); also dec_bf[b][s][e] = bf16(dec)
        const int b = bid >> 5, rem = bid & 31;
        const int s0 = (rem >> 2) << 6, e0 = (rem & 3) << 6;
#pragma unroll
        for (int it = 0; it < 16; ++it) {
            int lin = threadIdx.x + it * 256;
            int sl = lin >> 6, el = lin & 63;
            int src = (b * HWXY + s0 + sl) * EE + e0 + el;
            float dv = dec[src];
            dec_bf[src] = f2bf(dv);
            tl[sl][el] = f2bf(enc[src] + dv);
        }
        __syncthreads();
#pragma unroll
        for (int it = 0; it < 16; ++it) {
            int lin = threadIdx.x + it * 256;
            int el = lin >> 6, sl = lin & 63;
            resT[(b * EE + e0 + el) * HWXY + s0 + sl] = tl[sl][el];
        }
        return;
    }
    bid -= 512;
    if (bid < 96) {
        // convwT[j][cin] = bf16(conv_w[cin][j]), cin=768, j=512
        const int c0 = (bid >> 3) << 6, j0 = (bid & 7) << 6;
#pragma unroll
        for (int it = 0; it < 16; ++it) {
            int lin = threadIdx.x + it * 256;
            int cl = lin >> 6, jl = lin & 63;
            tl[cl][jl] = f2bf(conv_w[(c0 + cl) * 512 + j0 + jl]);
        }
        __syncthreads();
#pragma unroll
        for (int it = 0; it < 16; ++it) {
            int lin = threadIdx.x + it * 256;
            int jl = lin >> 6, cl = lin & 63;
            convwT[(j0 + jl) * 768 + c0 + cl] = tl[cl][jl];
        }
        return;
    }
    bid -= 96;
    int i8 = (bid * 256 + threadIdx.x) * 8;
    const int n1 = BB * TT * EE;   // 262144
    const int n2 = EE * EE;        // 65536
    if (i8 < n1) {
        int b = i8 >> 14, t = (i8 >> 8) & 63, e = i8 & 255;
        int lab = labels[b * TT + t];
        const float* ep = embed + lab * EE + e;
        float4 v0 = *(const float4*)ep, v1 = *(const float4*)(ep + 4);
        *(float4*)(s_f32 + i8) = v0;
        *(float4*)(s_f32 + i8 + 4) = v1;
        *(u16x8*)(a_bf + i8) = pack8(v0, v1);
        return;
    }
    i8 -= n1;
    if (i8 < n2) {
        float4 v0 = *(const float4*)(W_w + i8), v1 = *(const float4*)(W_w + i8 + 4);
        *(u16x8*)(W_bf + i8) = pack8(v0, v1);
        return;
    }
    i8 -= n2;
    float4 v0 = *(const float4*)(Wo_w + i8), v1 = *(const float4*)(Wo_w + i8 + 4);
    *(u16x8*)(Wo_bf + i8) = pack8(v0, v1);
}

// ---------------------------------------------------------------------------
// Fused layer: conv+GLU -> h -> scores -> softmax -> c -> a (+ logits if LAST)
// grid 64 = (b, t-tile of 16). block 512 (8 waves).
// Frag-ordered LDS: element (m,k) at byte (k>>3)*256 + m*16 + (k&7)*2 so the
// MFMA A-read is lds + kc*1024 + lane*16 (lane-linear, conflict-free).
// ---------------------------------------------------------------------------
template <int LAST>
__global__ __launch_bounds__(512) void k_layer(
    const unsigned short* __restrict__ a_in, unsigned short* __restrict__ a_out,
    const unsigned short* __restrict__ convwT, const float* __restrict__ conv_b,
    const unsigned short* __restrict__ W_bf, const float* __restrict__ W_b,
    const float* __restrict__ s_f32, const unsigned short* __restrict__ dec_bf,
    const unsigned short* __restrict__ resT, const unsigned short* __restrict__ Wo_bf,
    const float* __restrict__ Wo_b, float* __restrict__ out) {
    __shared__ __align__(16) char z_lds[8192];    // z frag, K=256 (reused for a if LAST)
    __shared__ __align__(16) char h_lds[8192];    // h frag, K=256
    __shared__ __align__(16) char p_lds[16384];   // alpha frag, K=512
    __shared__ float red_m[16][8];
    __shared__ float red_s[16][8];

    const int b = blockIdx.x >> 2, t0 = (blockIdx.x & 3) << 4;
    const int w = threadIdx.x >> 6, L = threadIdx.x & 63;
    const int l16 = L & 15, lg = L >> 4;

    // ---- Phase A: conv(K=3, E->2E) + GLU. wave owns 32 pair-cols.
    f32x4 za[2] = {{0.f,0.f,0.f,0.f},{0.f,0.f,0.f,0.f}};
    f32x4 zb[2] = {{0.f,0.f,0.f,0.f},{0.f,0.f,0.f,0.f}};
    const int tA = t0 + l16;
    for (int kc = 0; kc < 24; ++kc) {
        const int kt = kc >> 3, e0 = (kc & 7) << 5;
        const int ts = tA + kt - 1;
        u16x8 au = {0,0,0,0,0,0,0,0};
        if (ts >= 0 && ts < TT)
            au = *(const u16x8*)(a_in + (b * TT + ts) * EE + e0 + lg * 8);
        bf16x8 af = __builtin_bit_cast(bf16x8, au);
        const int k0 = kc << 5;
#pragma unroll
        for (int nf = 0; nf < 2; ++nf) {
            const int p = w * 32 + nf * 16 + l16;
            za[nf] = mfma16(af, load_bf8(convwT + p * 768 + k0 + lg * 8), za[nf]);
            zb[nf] = mfma16(af, load_bf8(convwT + (p + 256) * 768 + k0 + lg * 8), zb[nf]);
        }
    }
    float zf[2][4];
#pragma unroll
    for (int nf = 0; nf < 2; ++nf) {
        const int col = w * 32 + nf * 16 + l16;
        const float cbA = conv_b[col], cbB = conv_b[col + 256];
#pragma unroll
        for (int j = 0; j < 4; ++j) {
            const float vA = za[nf][j] + cbA, vB = zb[nf][j] + cbB;
            const float zv = vA / (1.0f + __expf(-vB));
            zf[nf][j] = zv;
            const int row = lg * 4 + j;
            *(unsigned short*)(z_lds + ((col >> 3) << 8) + row * 16 + ((col & 7) << 1)) = f2bf(zv);
        }
    }
    __syncthreads();

    // ---- Phase B: h = z @ W^T + W_b + s. wave owns 32 cols.
    f32x4 ha[2] = {{0.f,0.f,0.f,0.f},{0.f,0.f,0.f,0.f}};
    for (int kc = 0; kc < 8; ++kc) {
        const bf16x8 af = *(const bf16x8*)(z_lds + kc * 1024 + L * 16);
#pragma unroll
        for (int nf = 0; nf < 2; ++nf) {
            const int c = w * 32 + nf * 16 + l16;
            ha[nf] = mfma16(af, load_bf8(W_bf + c * EE + kc * 32 + lg * 8), ha[nf]);
        }
    }
#pragma unroll
    for (int nf = 0; nf < 2; ++nf) {
        const int c = w * 32 + nf * 16 + l16;
        const float wb = W_b[c];
#pragma unroll
        for (int j = 0; j < 4; ++j) {
            const int row = lg * 4 + j;
            const float hv = ha[nf][j] + wb + s_f32[(b * TT + t0 + row) * EE + c];
            *(unsigned short*)(h_lds + ((c >> 3) << 8) + row * 16 + ((c & 7) << 1)) = f2bf(hv);
        }
    }
    __syncthreads();

    // ---- Phase C: scores = h . dec^T. wave owns 64 s-cols.
    f32x4 sc[4] = {{0.f,0.f,0.f,0.f},{0.f,0.f,0.f,0.f},{0.f,0.f,0.f,0.f},{0.f,0.f,0.f,0.f}};
    for (int kc = 0; kc < 8; ++kc) {
        const bf16x8 af = *(const bf16x8*)(h_lds + kc * 1024 + L * 16);
#pragma unroll
        for (int nf = 0; nf < 4; ++nf) {
            const int srow = w * 64 + nf * 16 + l16;
            sc[nf] = mfma16(af, load_bf8(dec_bf + (b * HWXY + srow) * EE + kc * 32 + lg * 8), sc[nf]);
        }
    }
    // softmax over s=512: wave-local max -> LDS -> global max -> p -> sums
#pragma unroll
    for (int j = 0; j < 4; ++j) {
        float m = sc[0][j];
#pragma unroll
        for (int nf = 1; nf < 4; ++nf) m = fmaxf(m, sc[nf][j]);
#pragma unroll
        for (int off = 8; off >= 1; off >>= 1) m = fmaxf(m, __shfl_xor(m, off));
        if (l16 == 0) red_m[lg * 4 + j][w] = m;
    }
    __syncthreads();
    float sm[4];
#pragma unroll
    for (int j = 0; j < 4; ++j) {
        const int row = lg * 4 + j;
        float m = red_m[row][0];
#pragma unroll
        for (int ww = 1; ww < 8; ++ww) m = fmaxf(m, red_m[row][ww]);
        float s = 0.f;
#pragma unroll
        for (int nf = 0; nf < 4; ++nf) {
            const float p = __expf(sc[nf][j] - m);
            sc[nf][j] = p;
            s += p;
        }
#pragma unroll
        for (int off = 8; off >= 1; off >>= 1) s += __shfl_xor(s, off);
        sm[j] = s;
    }
    if (l16 == 0)
#pragma unroll
        for (int j = 0; j < 4; ++j) red_s[lg * 4 + j][w] = sm[j];
    // store UNNORMALIZED p (<=1) to frag LDS; normalize via inv at c-accum
#pragma unroll
    for (int nf = 0; nf < 4; ++nf) {
        const int col = w * 64 + nf * 16 + l16;
#pragma unroll
        for (int j = 0; j < 4; ++j) {
            const int row = lg * 4 + j;
            *(unsigned short*)(p_lds + ((col >> 3) << 8) + row * 16 + ((col & 7) << 1)) = f2bf(sc[nf][j]);
        }
    }
    __syncthreads();
    float inv[4];
#pragma unroll
    for (int j = 0; j < 4; ++j) {
        const int row = lg * 4 + j;
        float s = 0.f;
#pragma unroll
        for (int ww = 0; ww < 8; ++ww) s += red_s[row][ww];
        inv[j] = 1.0f / s;
    }

    // ---- Phase D: c = alpha . res^T (K=512); a = c*inv + z. wave owns 32 e-cols.
    f32x4 ca[2] = {{0.f,0.f,0.f,0.f},{0.f,0.f,0.f,0.f}};
    for (int kc = 0; kc < 16; ++kc) {
        const bf16x8 af = *(const bf16x8*)(p_lds + kc * 1024 + L * 16);
#pragma unroll
        for (int nf = 0; nf < 2; ++nf) {
            const int e = w * 32 + nf * 16 + l16;
            ca[nf] = mfma16(af, load_bf8(resT + (b * EE + e) * HWXY + kc * 32 + lg * 8), ca[nf]);
        }
    }
    if (!LAST) {
#pragma unroll
        for (int nf = 0; nf < 2; ++nf) {
            const int e = w * 32 + nf * 16 + l16;
#pragma unroll
            for (int j = 0; j < 4; ++j) {
                const int row = lg * 4 + j;
                a_out[(b * TT + t0 + row) * EE + e] = f2bf(ca[nf][j] * inv[j] + zf[nf][j]);
            }
        }
    } else {
        // a -> frag LDS (reuse z_lds; its last read was Phase B, >=2 barriers ago)
#pragma unroll
        for (int nf = 0; nf < 2; ++nf) {
            const int col = w * 32 + nf * 16 + l16;
#pragma unroll
            for (int j = 0; j < 4; ++j) {
                const int row = lg * 4 + j;
                *(unsigned short*)(z_lds + ((col >> 3) << 8) + row * 16 + ((col & 7) << 1)) =
                    f2bf(ca[nf][j] * inv[j] + zf[nf][j]);
            }
        }
        __syncthreads();
        // ---- Phase E: logits = a @ Wo^T + Wo_b; log_softmax over V=128.
        f32x4 la = {0.f,0.f,0.f,0.f};
        const int v = w * 16 + l16;
        for (int kc = 0; kc < 8; ++kc) {
            const bf16x8 af = *(const bf16x8*)(z_lds + kc * 1024 + L * 16);
            la = mfma16(af, load_bf8(Wo_bf + v * EE + kc * 32 + lg * 8), la);
        }
        const float wb = Wo_b[v];
        float lv[4];
#pragma unroll
        for (int j = 0; j < 4; ++j) {
            lv[j] = la[j] + wb;
            float m = lv[j];
#pragma unroll
            for (int off = 8; off >= 1; off >>= 1) m = fmaxf(m, __shfl_xor(m, off));
            if (l16 == 0) red_m[lg * 4 + j][w] = m;
        }
        __syncthreads();
        float mg[4], s4[4];
#pragma unroll
        for (int j = 0; j < 4; ++j) {
            const int row = lg * 4 + j;
            float m = red_m[row][0];
#pragma unroll
            for (int ww = 1; ww < 8; ++ww) m = fmaxf(m, red_m[row][ww]);
            mg[j] = m;
            float s = __expf(lv[j] - m);
#pragma unroll
            for (int off = 8; off >= 1; off >>= 1) s += __shfl_xor(s, off);
            s4[j] = s;
        }
        if (l16 == 0)
#pragma unroll
            for (int j = 0; j < 4; ++j) red_s[lg * 4 + j][w] = s4[j];
        __syncthreads();
#pragma unroll
        for (int j = 0; j < 4; ++j) {
            const int row = lg * 4 + j;
            float s = 0.f;
#pragma unroll
            for (int ww = 0; ww < 8; ++ww) s += red_s[row][ww];
            const float lse = mg[j] + __logf(s);
            out[(b * TT + t0 + row) * VV + v] = lv[j] - lse;
        }
    }
}

// ---------------------------------------------------------------------------
extern "C" void kernel_launch(void* const* d_in, const int* in_sizes, int n_in,
                              void* d_out, int out_size, void* d_ws, size_t ws_size,
                              hipStream_t stream) {
    const float* enc    = (const float*)d_in[0];
    const float* dec    = (const float*)d_in[1];
    const int*   labels = (const int*)d_in[2];
    const float* embed  = (const float*)d_in[3];
    const float* conv_w = (const float*)d_in[4];
    const float* conv_b = (const float*)d_in[5];
    const float* W_w    = (const float*)d_in[6];
    const float* W_b    = (const float*)d_in[7];
    const float* Wo_w   = (const float*)d_in[8];
    const float* Wo_b   = (const float*)d_in[9];
    float* out = (float*)d_out;
    char* ws = (char*)d_ws;

    float*          s_f32  = (float*)(ws + 0x000000);           // 1 MB
    unsigned short* a0     = (unsigned short*)(ws + 0x100000);   // 512 KB
    unsigned short* a1     = (unsigned short*)(ws + 0x180000);   // 512 KB
    unsigned short* dec_bf = (unsigned short*)(ws + 0x200000);   // 4 MB
    unsigned short* resT   = (unsigned short*)(ws + 0x600000);   // 4 MB
    unsigned short* convwT = (unsigned short*)(ws + 0xA00000);   // 768 KB
    unsigned short* W_bf   = (unsigned short*)(ws + 0xAC0000);   // 128 KB
    unsigned short* Wo_bf  = (unsigned short*)(ws + 0xAE0000);   // 64 KB

    k_setup<<<784, 256, 0, stream>>>(enc, dec, labels, embed, conv_w, W_w, Wo_w,
                                     s_f32, a0, dec_bf, resT, convwT, W_bf, Wo_bf);

    k_layer<0><<<64, 512, 0, stream>>>(a0, a1, convwT, conv_b, W_bf, W_b, s_f32,
                                       dec_bf, resT, Wo_bf, Wo_b, out);
    k_layer<0><<<64, 512, 0, stream>>>(a1, a0, convwT, conv_b, W_bf, W_b, s_f32,
                                       dec_bf, resT, Wo_bf, Wo_b, out);
    k_layer<1><<<64, 512, 0, stream>>>(a0, a1, convwT, conv_b, W_bf, W_b, s_f32,
                                       dec_bf, resT, Wo_bf, Wo_b, out);
}

// Round 3
// 148.830 us; speedup vs baseline: 1.3144x; 1.0875x over previous
//
#include <hip/hip_runtime.h>
#include <hip/hip_bf16.h>
#include <math.h>

#define BB 16
#define TT 64
#define HWXY 512
#define EE 256
#define VV 128

typedef __bf16 bf16x8 __attribute__((ext_vector_type(8)));
typedef unsigned short u16x8 __attribute__((ext_vector_type(8)));
typedef float f32x4 __attribute__((ext_vector_type(4)));

__device__ __forceinline__ f32x4 mfma16(bf16x8 a, bf16x8 b, f32x4 c) {
    return __builtin_amdgcn_mfma_f32_16x16x32_bf16(a, b, c, 0, 0, 0);
}

__device__ __forceinline__ unsigned short f2bf(float f) {
    union { float f; unsigned int i; } v; v.f = f;
    unsigned int x = v.i;
    return (unsigned short)((x + 0x7fffu + ((x >> 16) & 1u)) >> 16);  // RNE
}

__device__ __forceinline__ bf16x8 load_bf8(const unsigned short* p) {
    return __builtin_bit_cast(bf16x8, *(const u16x8*)p);
}

__device__ __forceinline__ u16x8 pack8(float4 v0, float4 v1) {
    u16x8 o;
    o[0] = f2bf(v0.x); o[1] = f2bf(v0.y); o[2] = f2bf(v0.z); o[3] = f2bf(v0.w);
    o[4] = f2bf(v1.x); o[5] = f2bf(v1.y); o[6] = f2bf(v1.z); o[7] = f2bf(v1.w);
    return o;
}

// frag-ordered LDS store: element (row, col) -> byte (col>>3)*256 + row*16 + (col&7)*2
__device__ __forceinline__ void frag_store(char* lds, int col, int row, unsigned short v) {
    *(unsigned short*)(lds + ((col >> 3) << 8) + row * 16 + ((col & 7) << 1)) = v;
}

// ---------------------------------------------------------------------------
// Setup (unchanged from round 2): LDS-tiled transposes + vectorized elementwise
// ---------------------------------------------------------------------------
__global__ __launch_bounds__(256) void k_setup(
    const float* __restrict__ enc, const float* __restrict__ dec,
    const int* __restrict__ labels, const float* __restrict__ embed,
    const float* __restrict__ conv_w, const float* __restrict__ W_w,
    const float* __restrict__ Wo_w,
    float* __restrict__ s_f32, unsigned short* __restrict__ a_bf,
    unsigned short* __restrict__ dec_bf, unsigned short* __restrict__ resT,
    unsigned short* __restrict__ convwT, unsigned short* __restrict__ W_bf,
    unsigned short* __restrict__ Wo_bf) {
    __shared__ unsigned short tl[64][66];
    int bid = blockIdx.x;
    if (bid < 512) {
        const int b = bid >> 5, rem = bid & 31;
        const int s0 = (rem >> 2) << 6, e0 = (rem & 3) << 6;
#pragma unroll
        for (int it = 0; it < 16; ++it) {
            int lin = threadIdx.x + it * 256;
            int sl = lin >> 6, el = lin & 63;
            int src = (b * HWXY + s0 + sl) * EE + e0 + el;
            float dv = dec[src];
            dec_bf[src] = f2bf(dv);
            tl[sl][el] = f2bf(enc[src] + dv);
        }
        __syncthreads();
#pragma unroll
        for (int it = 0; it < 16; ++it) {
            int lin = threadIdx.x + it * 256;
            int el = lin >> 6, sl = lin & 63;
            resT[(b * EE + e0 + el) * HWXY + s0 + sl] = tl[sl][el];
        }
        return;
    }
    bid -= 512;
    if (bid < 96) {
        const int c0 = (bid >> 3) << 6, j0 = (bid & 7) << 6;
#pragma unroll
        for (int it = 0; it < 16; ++it) {
            int lin = threadIdx.x + it * 256;
            int cl = lin >> 6, jl = lin & 63;
            tl[cl][jl] = f2bf(conv_w[(c0 + cl) * 512 + j0 + jl]);
        }
        __syncthreads();
#pragma unroll
        for (int it = 0; it < 16; ++it) {
            int lin = threadIdx.x + it * 256;
            int jl = lin >> 6, cl = lin & 63;
            convwT[(j0 + jl) * 768 + c0 + cl] = tl[cl][jl];
        }
        return;
    }
    bid -= 96;
    int i8 = (bid * 256 + threadIdx.x) * 8;
    const int n1 = BB * TT * EE;
    const int n2 = EE * EE;
    if (i8 < n1) {
        int b = i8 >> 14, t = (i8 >> 8) & 63, e = i8 & 255;
        int lab = labels[b * TT + t];
        const float* ep = embed + lab * EE + e;
        float4 v0 = *(const float4*)ep, v1 = *(const float4*)(ep + 4);
        *(float4*)(s_f32 + i8) = v0;
        *(float4*)(s_f32 + i8 + 4) = v1;
        *(u16x8*)(a_bf + i8) = pack8(v0, v1);
        return;
    }
    i8 -= n1;
    if (i8 < n2) {
        float4 v0 = *(const float4*)(W_w + i8), v1 = *(const float4*)(W_w + i8 + 4);
        *(u16x8*)(W_bf + i8) = pack8(v0, v1);
        return;
    }
    i8 -= n2;
    float4 v0 = *(const float4*)(Wo_w + i8), v1 = *(const float4*)(Wo_w + i8 + 4);
    *(u16x8*)(Wo_bf + i8) = pack8(v0, v1);
}

// ---------------------------------------------------------------------------
// Fused layer. grid 64 = (b, t-tile 16). block 1024 (16 waves, 4 waves/SIMD).
// ---------------------------------------------------------------------------
template <int LAST>
__global__ __launch_bounds__(1024) void k_layer(
    const unsigned short* __restrict__ a_in, unsigned short* __restrict__ a_out,
    const unsigned short* __restrict__ convwT, const float* __restrict__ conv_b,
    const unsigned short* __restrict__ W_bf, const float* __restrict__ W_b,
    const float* __restrict__ s_f32, const unsigned short* __restrict__ dec_bf,
    const unsigned short* __restrict__ resT, const unsigned short* __restrict__ Wo_bf,
    const float* __restrict__ Wo_b, float* __restrict__ out) {
    __shared__ __align__(16) char a_lds[18 * 512];   // halo tile, XOR-swizzled 16B slots
    __shared__ __align__(16) char z_lds[8192];       // z frags (reused for a if LAST)
    __shared__ __align__(16) char h_lds[8192];       // h frags
    __shared__ __align__(16) char p_lds[16384];      // alpha frags, K=512
    __shared__ float red_m[16][16];
    __shared__ float red_s[16][16];

    const int b = blockIdx.x >> 2, t0 = (blockIdx.x & 3) << 4;
    const int tid = threadIdx.x;
    const int w = tid >> 6, L = tid & 63;
    const int l16 = L & 15, lg = L >> 4;

    // ---- Stage a halo tile (rows t0-1 .. t0+16) into swizzled LDS
    if (tid < 576) {
        const int row = tid >> 5, chunk = tid & 31;
        const int t = t0 - 1 + row;
        u16x8 v = {0,0,0,0,0,0,0,0};
        if (t >= 0 && t < TT) v = *(const u16x8*)(a_in + (b * TT + t) * EE + chunk * 8);
        *(u16x8*)(a_lds + row * 512 + ((chunk * 16) ^ ((row & 7) << 4))) = v;
    }
    __syncthreads();

    // ---- Phase A: conv(K=3, E->2E) + GLU. wave owns 16 pair-cols.
    f32x4 za = {0.f,0.f,0.f,0.f}, zb = {0.f,0.f,0.f,0.f};
    const unsigned short* cwA = convwT + (w * 16 + l16) * 768 + lg * 8;
    const unsigned short* cwB = cwA + 256 * 768;
#pragma unroll
    for (int kt = 0; kt < 3; ++kt) {
        const int arow = l16 + kt;
        const char* rbase = a_lds + arow * 512;
        const int swz = (arow & 7) << 4;
#pragma unroll
        for (int ec = 0; ec < 8; ++ec) {
            const bf16x8 af = *(const bf16x8*)(rbase + ((ec * 64 + lg * 16) ^ swz));
            za = mfma16(af, load_bf8(cwA + kt * 256 + ec * 32), za);
            zb = mfma16(af, load_bf8(cwB + kt * 256 + ec * 32), zb);
        }
    }
    float zf[4];
    {
        const int col = w * 16 + l16;
        const float cbA = conv_b[col], cbB = conv_b[col + 256];
#pragma unroll
        for (int j = 0; j < 4; ++j) {
            const float vA = za[j] + cbA, vB = zb[j] + cbB;
            const float zv = vA / (1.0f + __expf(-vB));
            zf[j] = zv;
            frag_store(z_lds, col, lg * 4 + j, f2bf(zv));
        }
    }
    __syncthreads();

    // ---- Phase B: h = z @ W^T + W_b + s. wave owns 16 cols.
    f32x4 ha = {0.f,0.f,0.f,0.f};
    {
        const unsigned short* wp = W_bf + (w * 16 + l16) * EE + lg * 8;
#pragma unroll
        for (int kc = 0; kc < 8; ++kc) {
            const bf16x8 af = *(const bf16x8*)(z_lds + kc * 1024 + L * 16);
            ha = mfma16(af, load_bf8(wp + kc * 32), ha);
        }
        const int c = w * 16 + l16;
        const float wb = W_b[c];
#pragma unroll
        for (int j = 0; j < 4; ++j) {
            const int row = lg * 4 + j;
            const float hv = ha[j] + wb + s_f32[(b * TT + t0 + row) * EE + c];
            frag_store(h_lds, c, row, f2bf(hv));
        }
    }
    __syncthreads();

    // ---- Phase C: scores = h . dec^T. wave owns 32 s-cols (2 frags).
    f32x4 sc[2] = {{0.f,0.f,0.f,0.f},{0.f,0.f,0.f,0.f}};
    {
        const unsigned short* dp0 = dec_bf + (b * HWXY + w * 32 + l16) * EE + lg * 8;
        const unsigned short* dp1 = dp0 + 16 * EE;
#pragma unroll
        for (int kc = 0; kc < 8; ++kc) {
            const bf16x8 af = *(const bf16x8*)(h_lds + kc * 1024 + L * 16);
            sc[0] = mfma16(af, load_bf8(dp0 + kc * 32), sc[0]);
            sc[1] = mfma16(af, load_bf8(dp1 + kc * 32), sc[1]);
        }
    }
    // softmax over s=512 across 16 waves
#pragma unroll
    for (int j = 0; j < 4; ++j) {
        float m = fmaxf(sc[0][j], sc[1][j]);
#pragma unroll
        for (int off = 8; off >= 1; off >>= 1) m = fmaxf(m, __shfl_xor(m, off));
        if (l16 == 0) red_m[lg * 4 + j][w] = m;
    }
    __syncthreads();
    float sm[4];
#pragma unroll
    for (int j = 0; j < 4; ++j) {
        const int row = lg * 4 + j;
        float m = red_m[row][0];
#pragma unroll
        for (int ww = 1; ww < 16; ++ww) m = fmaxf(m, red_m[row][ww]);
        const float p0 = __expf(sc[0][j] - m);
        const float p1 = __expf(sc[1][j] - m);
        sc[0][j] = p0; sc[1][j] = p1;
        float s = p0 + p1;
#pragma unroll
        for (int off = 8; off >= 1; off >>= 1) s += __shfl_xor(s, off);
        sm[j] = s;
    }
    if (l16 == 0)
#pragma unroll
        for (int j = 0; j < 4; ++j) red_s[lg * 4 + j][w] = sm[j];
    // unnormalized p -> frag LDS (normalize at the c-accumulator)
#pragma unroll
    for (int nf = 0; nf < 2; ++nf) {
        const int col = w * 32 + nf * 16 + l16;
#pragma unroll
        for (int j = 0; j < 4; ++j)
            frag_store(p_lds, col, lg * 4 + j, f2bf(sc[nf][j]));
    }
    __syncthreads();
    float inv[4];
#pragma unroll
    for (int j = 0; j < 4; ++j) {
        const int row = lg * 4 + j;
        float s = 0.f;
#pragma unroll
        for (int ww = 0; ww < 16; ++ww) s += red_s[row][ww];
        inv[j] = 1.0f / s;
    }

    // ---- Phase D: c = alpha . res^T (K=512); a = c*inv + z. wave owns 16 e-cols.
    f32x4 ca = {0.f,0.f,0.f,0.f};
    {
        const unsigned short* rp = resT + (b * EE + w * 16 + l16) * HWXY + lg * 8;
#pragma unroll
        for (int kc = 0; kc < 16; ++kc) {
            const bf16x8 af = *(const bf16x8*)(p_lds + kc * 1024 + L * 16);
            ca = mfma16(af, load_bf8(rp + kc * 32), ca);
        }
    }
    if (!LAST) {
        const int e = w * 16 + l16;
#pragma unroll
        for (int j = 0; j < 4; ++j) {
            const int row = lg * 4 + j;
            a_out[(b * TT + t0 + row) * EE + e] = f2bf(ca[j] * inv[j] + zf[j]);
        }
    } else {
        const int col = w * 16 + l16;
#pragma unroll
        for (int j = 0; j < 4; ++j)
            frag_store(z_lds, col, lg * 4 + j, f2bf(ca[j] * inv[j] + zf[j]));
        __syncthreads();
        // ---- Phase E: logits = a @ Wo^T + Wo_b; log_softmax over V=128.
        float lv[4], mg[4];
        if (w < 8) {
            f32x4 la = {0.f,0.f,0.f,0.f};
            const int v = w * 16 + l16;
            const unsigned short* wo = Wo_bf + v * EE + lg * 8;
#pragma unroll
            for (int kc = 0; kc < 8; ++kc) {
                const bf16x8 af = *(const bf16x8*)(z_lds + kc * 1024 + L * 16);
                la = mfma16(af, load_bf8(wo + kc * 32), la);
            }
            const float wb = Wo_b[v];
#pragma unroll
            for (int j = 0; j < 4; ++j) {
                lv[j] = la[j] + wb;
                float m = lv[j];
#pragma unroll
                for (int off = 8; off >= 1; off >>= 1) m = fmaxf(m, __shfl_xor(m, off));
                if (l16 == 0) red_m[lg * 4 + j][w] = m;
            }
        }
        __syncthreads();
        if (w < 8) {
#pragma unroll
            for (int j = 0; j < 4; ++j) {
                const int row = lg * 4 + j;
                float m = red_m[row][0];
#pragma unroll
                for (int ww = 1; ww < 8; ++ww) m = fmaxf(m, red_m[row][ww]);
                mg[j] = m;
                float s = __expf(lv[j] - m);
#pragma unroll
                for (int off = 8; off >= 1; off >>= 1) s += __shfl_xor(s, off);
                if (l16 == 0) red_s[row][w] = s;
            }
        }
        __syncthreads();
        if (w < 8) {
            const int v = w * 16 + l16;
#pragma unroll
            for (int j = 0; j < 4; ++j) {
                const int row = lg * 4 + j;
                float s = 0.f;
#pragma unroll
                for (int ww = 0; ww < 8; ++ww) s += red_s[row][ww];
                const float lse = mg[j] + __logf(s);
                out[(b * TT + t0 + row) * VV + v] = lv[j] - lse;
            }
        }
    }
}

// ---------------------------------------------------------------------------
extern "C" void kernel_launch(void* const* d_in, const int* in_sizes, int n_in,
                              void* d_out, int out_size, void* d_ws, size_t ws_size,
                              hipStream_t stream) {
    const float* enc    = (const float*)d_in[0];
    const float* dec    = (const float*)d_in[1];
    const int*   labels = (const int*)d_in[2];
    const float* embed  = (const float*)d_in[3];
    const float* conv_w = (const float*)d_in[4];
    const float* conv_b = (const float*)d_in[5];
    const float* W_w    = (const float*)d_in[6];
    const float* W_b    = (const float*)d_in[7];
    const float* Wo_w   = (const float*)d_in[8];
    const float* Wo_b   = (const float*)d_in[9];
    float* out = (float*)d_out;
    char* ws = (char*)d_ws;

    float*          s_f32  = (float*)(ws + 0x000000);
    unsigned short* a0     = (unsigned short*)(ws + 0x100000);
    unsigned short* a1     = (unsigned short*)(ws + 0x180000);
    unsigned short* dec_bf = (unsigned short*)(ws + 0x200000);
    unsigned short* resT   = (unsigned short*)(ws + 0x600000);
    unsigned short* convwT = (unsigned short*)(ws + 0xA00000);
    unsigned short* W_bf   = (unsigned short*)(ws + 0xAC0000);
    unsigned short* Wo_bf  = (unsigned short*)(ws + 0xAE0000);

    k_setup<<<784, 256, 0, stream>>>(enc, dec, labels, embed, conv_w, W_w, Wo_w,
                                     s_f32, a0, dec_bf, resT, convwT, W_bf, Wo_bf);

    k_layer<0><<<64, 1024, 0, stream>>>(a0, a1, convwT, conv_b, W_bf, W_b, s_f32,
                                        dec_bf, resT, Wo_bf, Wo_b, out);
    k_layer<0><<<64, 1024, 0, stream>>>(a1, a0, convwT, conv_b, W_bf, W_b, s_f32,
                                        dec_bf, resT, Wo_bf, Wo_b, out);
    k_layer<1><<<64, 1024, 0, stream>>>(a0, a1, convwT, conv_b, W_bf, W_b, s_f32,
                                        dec_bf, resT, Wo_bf, Wo_b, out);
}

// Round 4
// 145.957 us; speedup vs baseline: 1.3402x; 1.0197x over previous
//
#include <hip/hip_runtime.h>
#include <hip/hip_bf16.h>
#include <math.h>

#define BB 16
#define TT 64
#define HWXY 512
#define EE 256
#define VV 128

typedef __bf16 bf16x8 __attribute__((ext_vector_type(8)));
typedef unsigned short u16x8 __attribute__((ext_vector_type(8)));
typedef float f32x4 __attribute__((ext_vector_type(4)));

__device__ __forceinline__ f32x4 mfma16(bf16x8 a, bf16x8 b, f32x4 c) {
    return __builtin_amdgcn_mfma_f32_16x16x32_bf16(a, b, c, 0, 0, 0);
}

__device__ __forceinline__ bf16x8 bc(u16x8 v) { return __builtin_bit_cast(bf16x8, v); }

__device__ __forceinline__ unsigned short f2bf(float f) {
    union { float f; unsigned int i; } v; v.f = f;
    unsigned int x = v.i;
    return (unsigned short)((x + 0x7fffu + ((x >> 16) & 1u)) >> 16);  // RNE
}

__device__ __forceinline__ float bf2f(unsigned short u) {
    union { unsigned int i; float f; } v; v.i = ((unsigned int)u) << 16;
    return v.f;
}

__device__ __forceinline__ u16x8 pack8(float4 v0, float4 v1) {
    u16x8 o;
    o[0] = f2bf(v0.x); o[1] = f2bf(v0.y); o[2] = f2bf(v0.z); o[3] = f2bf(v0.w);
    o[4] = f2bf(v1.x); o[5] = f2bf(v1.y); o[6] = f2bf(v1.z); o[7] = f2bf(v1.w);
    return o;
}

// frag-ordered LDS store: element (row, col) -> byte (col>>3)*256 + row*16 + (col&7)*2
__device__ __forceinline__ void frag_store(char* lds, int col, int row, unsigned short v) {
    *(unsigned short*)(lds + ((col >> 3) << 8) + row * 16 + ((col & 7) << 1)) = v;
}

// ---------------------------------------------------------------------------
// Setup: LDS-tiled transposes (resT, convwT) + vectorized elementwise
// ---------------------------------------------------------------------------
__global__ __launch_bounds__(256) void k_setup(
    const float* __restrict__ enc, const float* __restrict__ dec,
    const int* __restrict__ labels, const float* __restrict__ embed,
    const float* __restrict__ conv_w, const float* __restrict__ W_w,
    const float* __restrict__ Wo_w,
    unsigned short* __restrict__ s_bf, unsigned short* __restrict__ a_bf,
    unsigned short* __restrict__ dec_bf, unsigned short* __restrict__ resT,
    unsigned short* __restrict__ convwT, unsigned short* __restrict__ W_bf,
    unsigned short* __restrict__ Wo_bf) {
    __shared__ unsigned short tl[64][66];
    int bid = blockIdx.x;
    if (bid < 512) {
        const int b = bid >> 5, rem = bid & 31;
        const int s0 = (rem >> 2) << 6, e0 = (rem & 3) << 6;
#pragma unroll
        for (int it = 0; it < 16; ++it) {
            int lin = threadIdx.x + it * 256;
            int sl = lin >> 6, el = lin & 63;
            int src = (b * HWXY + s0 + sl) * EE + e0 + el;
            float dv = dec[src];
            dec_bf[src] = f2bf(dv);
            tl[sl][el] = f2bf(enc[src] + dv);
        }
        __syncthreads();
#pragma unroll
        for (int it = 0; it < 16; ++it) {
            int lin = threadIdx.x + it * 256;
            int el = lin >> 6, sl = lin & 63;
            resT[(b * EE + e0 + el) * HWXY + s0 + sl] = tl[sl][el];
        }
        return;
    }
    bid -= 512;
    if (bid < 96) {
        const int c0 = (bid >> 3) << 6, j0 = (bid & 7) << 6;
#pragma unroll
        for (int it = 0; it < 16; ++it) {
            int lin = threadIdx.x + it * 256;
            int cl = lin >> 6, jl = lin & 63;
            tl[cl][jl] = f2bf(conv_w[(c0 + cl) * 512 + j0 + jl]);
        }
        __syncthreads();
#pragma unroll
        for (int it = 0; it < 16; ++it) {
            int lin = threadIdx.x + it * 256;
            int jl = lin >> 6, cl = lin & 63;
            convwT[(j0 + jl) * 768 + c0 + cl] = tl[cl][jl];
        }
        return;
    }
    bid -= 96;
    int i8 = (bid * 256 + threadIdx.x) * 8;
    const int n1 = BB * TT * EE;
    const int n2 = EE * EE;
    if (i8 < n1) {
        int b = i8 >> 14, t = (i8 >> 8) & 63, e = i8 & 255;
        int lab = labels[b * TT + t];
        const float* ep = embed + lab * EE + e;
        float4 v0 = *(const float4*)ep, v1 = *(const float4*)(ep + 4);
        u16x8 p = pack8(v0, v1);
        *(u16x8*)(s_bf + i8) = p;
        *(u16x8*)(a_bf + i8) = p;
        return;
    }
    i8 -= n1;
    if (i8 < n2) {
        float4 v0 = *(const float4*)(W_w + i8), v1 = *(const float4*)(W_w + i8 + 4);
        *(u16x8*)(W_bf + i8) = pack8(v0, v1);
        return;
    }
    i8 -= n2;
    float4 v0 = *(const float4*)(Wo_w + i8), v1 = *(const float4*)(Wo_w + i8 + 4);
    *(u16x8*)(Wo_bf + i8) = pack8(v0, v1);
}

// ---------------------------------------------------------------------------
// Fused layer. grid 64, block 512 (8 waves). XCD-swizzled block mapping.
// Every global B-stream is software-pipelined with a depth-2-step register
// ring (8 x 16B loads in flight per wave).
// ---------------------------------------------------------------------------
template <int LAST>
__global__ __launch_bounds__(512) void k_layer(
    const unsigned short* __restrict__ a_in, unsigned short* __restrict__ a_out,
    const unsigned short* __restrict__ convwT, const float* __restrict__ conv_b,
    const unsigned short* __restrict__ W_bf, const float* __restrict__ W_b,
    const unsigned short* __restrict__ s_bf, const unsigned short* __restrict__ dec_bf,
    const unsigned short* __restrict__ resT, const unsigned short* __restrict__ Wo_bf,
    const float* __restrict__ Wo_b, float* __restrict__ out) {
    __shared__ __align__(16) char a_lds[18 * 512];   // conv halo tile, XOR-swizzled
    __shared__ __align__(16) char z_lds[8192];       // z frags (reused for a if LAST)
    __shared__ __align__(16) char h_lds[8192];       // h frags
    __shared__ __align__(16) char p_lds[16384];      // alpha frags, K=512
    __shared__ float red_m[16][8];
    __shared__ float red_s[16][8];

    // XCD swizzle: blocks with same (b mod 8) share an XCD -> dec/resT L2-resident
    const int x = blockIdx.x;
    const int b = (x & 7) + (((x >> 3) >> 2) << 3);
    const int t0 = ((x >> 3) & 3) << 4;
    const int tid = threadIdx.x;
    const int w = tid >> 6, L = tid & 63;
    const int l16 = L & 15, lg = L >> 4;

    // ---- Stage conv halo tile (rows t0-1 .. t0+16) into swizzled LDS
    for (int i = tid; i < 576; i += 512) {
        const int row = i >> 5, chunk = i & 31;
        const int t = t0 - 1 + row;
        u16x8 v = {0,0,0,0,0,0,0,0};
        if (t >= 0 && t < TT) v = *(const u16x8*)(a_in + (b * TT + t) * EE + chunk * 8);
        *(u16x8*)(a_lds + row * 512 + ((chunk * 16) ^ ((row & 7) << 4))) = v;
    }
    __syncthreads();

    // ---- Phase A: conv(K=3, E->2E) + GLU. wave owns 32 pair-cols (2 frags).
    f32x4 za0 = {0,0,0,0}, za1 = {0,0,0,0}, zb0 = {0,0,0,0}, zb1 = {0,0,0,0};
    {
        const unsigned short* pA0 = convwT + (w * 32 + l16) * 768 + lg * 8;
        const unsigned short* pA1 = pA0 + 16 * 768;
        const unsigned short* pB0 = pA0 + 196608;
        const unsigned short* pB1 = pA1 + 196608;
        u16x8 rb[2][4];
        rb[0][0] = *(const u16x8*)pA0;        rb[0][1] = *(const u16x8*)pA1;
        rb[0][2] = *(const u16x8*)pB0;        rb[0][3] = *(const u16x8*)pB1;
        rb[1][0] = *(const u16x8*)(pA0 + 32); rb[1][1] = *(const u16x8*)(pA1 + 32);
        rb[1][2] = *(const u16x8*)(pB0 + 32); rb[1][3] = *(const u16x8*)(pB1 + 32);
#pragma unroll
        for (int s = 0; s < 24; ++s) {
            const int arow = l16 + (s >> 3);
            const bf16x8 af = *(const bf16x8*)(
                a_lds + arow * 512 + ((((s & 7) * 64) + lg * 16) ^ ((arow & 7) << 4)));
            u16x8 b0 = rb[s & 1][0], b1 = rb[s & 1][1], b2 = rb[s & 1][2], b3 = rb[s & 1][3];
            if (s < 22) {
                rb[s & 1][0] = *(const u16x8*)(pA0 + (s + 2) * 32);
                rb[s & 1][1] = *(const u16x8*)(pA1 + (s + 2) * 32);
                rb[s & 1][2] = *(const u16x8*)(pB0 + (s + 2) * 32);
                rb[s & 1][3] = *(const u16x8*)(pB1 + (s + 2) * 32);
            }
            za0 = mfma16(af, bc(b0), za0);
            za1 = mfma16(af, bc(b1), za1);
            zb0 = mfma16(af, bc(b2), zb0);
            zb1 = mfma16(af, bc(b3), zb1);
        }
    }
    float zf[2][4];
    {
        const int c0 = w * 32 + l16, c1 = c0 + 16;
        const float cbA0 = conv_b[c0], cbB0 = conv_b[c0 + 256];
        const float cbA1 = conv_b[c1], cbB1 = conv_b[c1 + 256];
#pragma unroll
        for (int j = 0; j < 4; ++j) {
            const float v0 = za0[j] + cbA0, w0 = zb0[j] + cbB0;
            const float v1 = za1[j] + cbA1, w1 = zb1[j] + cbB1;
            const float z0 = v0 / (1.0f + __expf(-w0));
            const float z1 = v1 / (1.0f + __expf(-w1));
            zf[0][j] = z0; zf[1][j] = z1;
            frag_store(z_lds, c0, lg * 4 + j, f2bf(z0));
            frag_store(z_lds, c1, lg * 4 + j, f2bf(z1));
        }
    }
    __syncthreads();

    // ---- Phase B: h = z @ W^T + W_b + s. wave owns 32 cols (2 frags).
    {
        f32x4 h0 = {0,0,0,0}, h1 = {0,0,0,0};
        const unsigned short* wp0 = W_bf + (w * 32 + l16) * EE + lg * 8;
        const unsigned short* wp1 = wp0 + 16 * EE;
        u16x8 rw[2][2];
        rw[0][0] = *(const u16x8*)wp0;        rw[0][1] = *(const u16x8*)wp1;
        rw[1][0] = *(const u16x8*)(wp0 + 32); rw[1][1] = *(const u16x8*)(wp1 + 32);
#pragma unroll
        for (int s = 0; s < 8; ++s) {
            const bf16x8 af = *(const bf16x8*)(z_lds + s * 1024 + L * 16);
            u16x8 c0 = rw[s & 1][0], c1 = rw[s & 1][1];
            if (s < 6) {
                rw[s & 1][0] = *(const u16x8*)(wp0 + (s + 2) * 32);
                rw[s & 1][1] = *(const u16x8*)(wp1 + (s + 2) * 32);
            }
            h0 = mfma16(af, bc(c0), h0);
            h1 = mfma16(af, bc(c1), h1);
        }
        const int c0 = w * 32 + l16, c1 = c0 + 16;
        const float wb0 = W_b[c0], wb1 = W_b[c1];
#pragma unroll
        for (int j = 0; j < 4; ++j) {
            const int row = lg * 4 + j;
            const int base = (b * TT + t0 + row) * EE;
            frag_store(h_lds, c0, row, f2bf(h0[j] + wb0 + bf2f(s_bf[base + c0])));
            frag_store(h_lds, c1, row, f2bf(h1[j] + wb1 + bf2f(s_bf[base + c1])));
        }
    }
    __syncthreads();

    // ---- Phase C: scores = h . dec^T. wave owns 64 s-cols (4 frags).
    f32x4 sc[4] = {{0,0,0,0},{0,0,0,0},{0,0,0,0},{0,0,0,0}};
    {
        const unsigned short* dp0 = dec_bf + (b * HWXY + w * 64 + l16) * EE + lg * 8;
        const unsigned short* dp1 = dp0 + 16 * EE;
        const unsigned short* dp2 = dp0 + 32 * EE;
        const unsigned short* dp3 = dp0 + 48 * EE;
        u16x8 rd[2][4];
        rd[0][0] = *(const u16x8*)dp0;        rd[0][1] = *(const u16x8*)dp1;
        rd[0][2] = *(const u16x8*)dp2;        rd[0][3] = *(const u16x8*)dp3;
        rd[1][0] = *(const u16x8*)(dp0 + 32); rd[1][1] = *(const u16x8*)(dp1 + 32);
        rd[1][2] = *(const u16x8*)(dp2 + 32); rd[1][3] = *(const u16x8*)(dp3 + 32);
#pragma unroll
        for (int s = 0; s < 8; ++s) {
            const bf16x8 af = *(const bf16x8*)(h_lds + s * 1024 + L * 16);
            u16x8 d0 = rd[s & 1][0], d1 = rd[s & 1][1], d2 = rd[s & 1][2], d3 = rd[s & 1][3];
            if (s < 6) {
                rd[s & 1][0] = *(const u16x8*)(dp0 + (s + 2) * 32);
                rd[s & 1][1] = *(const u16x8*)(dp1 + (s + 2) * 32);
                rd[s & 1][2] = *(const u16x8*)(dp2 + (s + 2) * 32);
                rd[s & 1][3] = *(const u16x8*)(dp3 + (s + 2) * 32);
            }
            sc[0] = mfma16(af, bc(d0), sc[0]);
            sc[1] = mfma16(af, bc(d1), sc[1]);
            sc[2] = mfma16(af, bc(d2), sc[2]);
            sc[3] = mfma16(af, bc(d3), sc[3]);
        }
    }
    // softmax over s=512 across 8 waves
#pragma unroll
    for (int j = 0; j < 4; ++j) {
        float m = fmaxf(fmaxf(sc[0][j], sc[1][j]), fmaxf(sc[2][j], sc[3][j]));
#pragma unroll
        for (int off = 8; off >= 1; off >>= 1) m = fmaxf(m, __shfl_xor(m, off));
        if (l16 == 0) red_m[lg * 4 + j][w] = m;
    }
    __syncthreads();
    float sm[4];
#pragma unroll
    for (int j = 0; j < 4; ++j) {
        const int row = lg * 4 + j;
        float m = red_m[row][0];
#pragma unroll
        for (int ww = 1; ww < 8; ++ww) m = fmaxf(m, red_m[row][ww]);
        float s = 0.f;
#pragma unroll
        for (int nf = 0; nf < 4; ++nf) {
            const float p = __expf(sc[nf][j] - m);
            sc[nf][j] = p;
            s += p;
        }
#pragma unroll
        for (int off = 8; off >= 1; off >>= 1) s += __shfl_xor(s, off);
        sm[j] = s;
    }
    if (l16 == 0)
#pragma unroll
        for (int j = 0; j < 4; ++j) red_s[lg * 4 + j][w] = sm[j];
    // unnormalized p -> frag LDS (normalize at the c-accumulator)
#pragma unroll
    for (int nf = 0; nf < 4; ++nf) {
        const int col = w * 64 + nf * 16 + l16;
#pragma unroll
        for (int j = 0; j < 4; ++j)
            frag_store(p_lds, col, lg * 4 + j, f2bf(sc[nf][j]));
    }
    __syncthreads();
    float inv[4];
#pragma unroll
    for (int j = 0; j < 4; ++j) {
        const int row = lg * 4 + j;
        float s = 0.f;
#pragma unroll
        for (int ww = 0; ww < 8; ++ww) s += red_s[row][ww];
        inv[j] = 1.0f / s;
    }

    // ---- Phase D: c = alpha . res^T (K=512); a = c*inv + z. wave owns 32 e-cols.
    f32x4 ca0 = {0,0,0,0}, ca1 = {0,0,0,0};
    {
        const unsigned short* rp0 = resT + (b * EE + w * 32 + l16) * HWXY + lg * 8;
        const unsigned short* rp1 = rp0 + 16 * HWXY;
        u16x8 rr[2][2];
        rr[0][0] = *(const u16x8*)rp0;        rr[0][1] = *(const u16x8*)rp1;
        rr[1][0] = *(const u16x8*)(rp0 + 32); rr[1][1] = *(const u16x8*)(rp1 + 32);
#pragma unroll
        for (int s = 0; s < 16; ++s) {
            const bf16x8 af = *(const bf16x8*)(p_lds + s * 1024 + L * 16);
            u16x8 r0 = rr[s & 1][0], r1 = rr[s & 1][1];
            if (s < 14) {
                rr[s & 1][0] = *(const u16x8*)(rp0 + (s + 2) * 32);
                rr[s & 1][1] = *(const u16x8*)(rp1 + (s + 2) * 32);
            }
            ca0 = mfma16(af, bc(r0), ca0);
            ca1 = mfma16(af, bc(r1), ca1);
        }
    }
    if (!LAST) {
        const int e0 = w * 32 + l16;
#pragma unroll
        for (int j = 0; j < 4; ++j) {
            const int row = lg * 4 + j;
            unsigned short* ap = a_out + (b * TT + t0 + row) * EE;
            ap[e0]      = f2bf(ca0[j] * inv[j] + zf[0][j]);
            ap[e0 + 16] = f2bf(ca1[j] * inv[j] + zf[1][j]);
        }
    } else {
        const int c0 = w * 32 + l16;
#pragma unroll
        for (int j = 0; j < 4; ++j) {
            const int row = lg * 4 + j;
            frag_store(z_lds, c0, row, f2bf(ca0[j] * inv[j] + zf[0][j]));
            frag_store(z_lds, c0 + 16, row, f2bf(ca1[j] * inv[j] + zf[1][j]));
        }
        __syncthreads();
        // ---- Phase E: logits = a @ Wo^T + Wo_b; log_softmax over V=128.
        f32x4 la = {0,0,0,0};
        const int v = w * 16 + l16;
        {
            const unsigned short* wo = Wo_bf + v * EE + lg * 8;
            u16x8 rE[2];
            rE[0] = *(const u16x8*)wo;
            rE[1] = *(const u16x8*)(wo + 32);
#pragma unroll
            for (int s = 0; s < 8; ++s) {
                const bf16x8 af = *(const bf16x8*)(z_lds + s * 1024 + L * 16);
                u16x8 e0 = rE[s & 1];
                if (s < 6) rE[s & 1] = *(const u16x8*)(wo + (s + 2) * 32);
                la = mfma16(af, bc(e0), la);
            }
        }
        const float wb = Wo_b[v];
        float lv[4], mg[4];
#pragma unroll
        for (int j = 0; j < 4; ++j) {
            lv[j] = la[j] + wb;
            float m = lv[j];
#pragma unroll
            for (int off = 8; off >= 1; off >>= 1) m = fmaxf(m, __shfl_xor(m, off));
            if (l16 == 0) red_m[lg * 4 + j][w] = m;
        }
        __syncthreads();
#pragma unroll
        for (int j = 0; j < 4; ++j) {
            const int row = lg * 4 + j;
            float m = red_m[row][0];
#pragma unroll
            for (int ww = 1; ww < 8; ++ww) m = fmaxf(m, red_m[row][ww]);
            mg[j] = m;
            float s = __expf(lv[j] - m);
#pragma unroll
            for (int off = 8; off >= 1; off >>= 1) s += __shfl_xor(s, off);
            if (l16 == 0) red_s[row][w] = s;
        }
        __syncthreads();
#pragma unroll
        for (int j = 0; j < 4; ++j) {
            const int row = lg * 4 + j;
            float s = 0.f;
#pragma unroll
            for (int ww = 0; ww < 8; ++ww) s += red_s[row][ww];
            const float lse = mg[j] + __logf(s);
            out[(b * TT + t0 + row) * VV + v] = lv[j] - lse;
        }
    }
}

// ---------------------------------------------------------------------------
extern "C" void kernel_launch(void* const* d_in, const int* in_sizes, int n_in,
                              void* d_out, int out_size, void* d_ws, size_t ws_size,
                              hipStream_t stream) {
    const float* enc    = (const float*)d_in[0];
    const float* dec    = (const float*)d_in[1];
    const int*   labels = (const int*)d_in[2];
    const float* embed  = (const float*)d_in[3];
    const float* conv_w = (const float*)d_in[4];
    const float* conv_b = (const float*)d_in[5];
    const float* W_w    = (const float*)d_in[6];
    const float* W_b    = (const float*)d_in[7];
    const float* Wo_w   = (const float*)d_in[8];
    const float* Wo_b   = (const float*)d_in[9];
    float* out = (float*)d_out;
    char* ws = (char*)d_ws;

    unsigned short* a0     = (unsigned short*)(ws + 0x000000);   // 512 KB
    unsigned short* a1     = (unsigned short*)(ws + 0x080000);   // 512 KB
    unsigned short* s_bf   = (unsigned short*)(ws + 0x100000);   // 512 KB
    unsigned short* dec_bf = (unsigned short*)(ws + 0x180000);   // 4 MB
    unsigned short* resT   = (unsigned short*)(ws + 0x580000);   // 4 MB
    unsigned short* convwT = (unsigned short*)(ws + 0x980000);   // 768 KB
    unsigned short* W_bf   = (unsigned short*)(ws + 0xA40000);   // 128 KB
    unsigned short* Wo_bf  = (unsigned short*)(ws + 0xA60000);   // 64 KB

    k_setup<<<784, 256, 0, stream>>>(enc, dec, labels, embed, conv_w, W_w, Wo_w,
                                     s_bf, a0, dec_bf, resT, convwT, W_bf, Wo_bf);

    k_layer<0><<<64, 512, 0, stream>>>(a0, a1, convwT, conv_b, W_bf, W_b, s_bf,
                                       dec_bf, resT, Wo_bf, Wo_b, out);
    k_layer<0><<<64, 512, 0, stream>>>(a1, a0, convwT, conv_b, W_bf, W_b, s_bf,
                                       dec_bf, resT, Wo_bf, Wo_b, out);
    k_layer<1><<<64, 512, 0, stream>>>(a0, a1, convwT, conv_b, W_bf, W_b, s_bf,
                                       dec_bf, resT, Wo_bf, Wo_b, out);
}